// Round 2
// baseline (1301.065 us; speedup 1.0000x reference)
//
#include <hip/hip_runtime.h>
#include <stdint.h>

// H2GCN forward on MI355X (gfx950).
// Dtype-robust: a probe kernel detects (a) whether float tensors are f32 or bf16,
// (b) whether edge_index is int64 or int32, and writes device flags; all kernels
// branch wave-uniformly on the flags. f32 mode uses 3-term split-bf16 MFMA for
// f32-grade accuracy; bf16 mode loads bf16 directly (exact in bf16 MFMA).

typedef __bf16 bf16x8 __attribute__((ext_vector_type(8)));
typedef float  f32x4  __attribute__((ext_vector_type(4)));

#define NN   100000
#define EE   800000
#define IND  512
#define HID  64
#define ZD   320
#define CLS  40
#define NCH  98          // ceil(NN/1024)
#define NTILE (NN/16)    // 6250 row tiles of 16

static __device__ __forceinline__ float bf2f(unsigned short s) {
  unsigned int u = ((unsigned int)s) << 16;
  return __builtin_bit_cast(float, u);
}
static __device__ __forceinline__ unsigned short f2bf(float f) {
  unsigned int u = __builtin_bit_cast(unsigned int, f);
  u += 0x7FFFu + ((u >> 16) & 1u);   // RNE
  return (unsigned short)(u >> 16);
}
// scalar load from f32-or-bf16 array
static __device__ __forceinline__ float ldsc(const void* p, int i, int fm) {
  return fm ? ((const float*)p)[i] : bf2f(((const unsigned short*)p)[i]);
}
// split 8 consecutive f32 into hi/lo bf16 fragments
static __device__ __forceinline__ void split8(const float* p, bf16x8& hi, bf16x8& lo) {
  f32x4 u0 = *(const f32x4*)p;
  f32x4 u1 = *(const f32x4*)(p + 4);
  #pragma unroll
  for (int j = 0; j < 4; ++j) {
    float v0 = u0[j], v1 = u1[j];
    __bf16 h0 = (__bf16)v0, h1 = (__bf16)v1;
    hi[j] = h0;     lo[j] = (__bf16)(v0 - (float)h0);
    hi[4 + j] = h1; lo[4 + j] = (__bf16)(v1 - (float)h1);
  }
}

// ---------------- dtype probe ----------------
// flags[0]=1 -> float tensors are f32 (else bf16). flags[1]=1 -> edges int64.
__global__ void k_probe(const unsigned short* __restrict__ xs,
                        const int* __restrict__ ei, int* __restrict__ flags) {
  __shared__ int cnt_big, cnt_nz;
  if (threadIdx.x == 0) { cnt_big = 0; cnt_nz = 0; }
  __syncthreads();
  unsigned short u = xs[threadIdx.x];
  int expf = (u >> 7) & 0xFF;
  if (expf >= 0x8D) atomicAdd(&cnt_big, 1);      // |bf16| >= 2^14 (or NaN/Inf)
  if (threadIdx.x < 128 && ei[2 * threadIdx.x + 1] != 0) atomicAdd(&cnt_nz, 1);
  __syncthreads();
  if (threadIdx.x == 0) {
    flags[0] = (cnt_big >= 2) ? 1 : 0;
    flags[1] = (cnt_nz < 64) ? 1 : 0;
  }
}

// ---------------- graph build ----------------
__global__ void k_deg(const int* __restrict__ ei, const int* __restrict__ flags,
                      int* __restrict__ deg) {
  int es = flags[1] + 1;
  int e = blockIdx.x * 256 + threadIdx.x;
  if (e >= EE) return;
  int r = ei[(size_t)e * es], c = ei[(size_t)(EE + e) * es];
  if (r != c) { atomicAdd(&deg[r], 1); atomicAdd(&deg[c], 1); }
}

__global__ void k_chunksum(const int* __restrict__ deg, int* __restrict__ csum) {
  __shared__ int sd[1024];
  int i = blockIdx.x * 1024 + threadIdx.x;
  sd[threadIdx.x] = (i < NN) ? deg[i] : 0;
  __syncthreads();
  for (int s = 512; s > 0; s >>= 1) {
    if (threadIdx.x < s) sd[threadIdx.x] += sd[threadIdx.x + s];
    __syncthreads();
  }
  if (threadIdx.x == 0) csum[blockIdx.x] = sd[0];
}

__global__ void k_scanchunks(int* __restrict__ csum, int* __restrict__ total) {
  if (threadIdx.x == 0) {
    int acc = 0;
    for (int i = 0; i < NCH; ++i) { int v = csum[i]; csum[i] = acc; acc += v; }
    total[0] = acc;
  }
}

__global__ void k_offs(const int* __restrict__ deg, const int* __restrict__ cbase,
                       int* __restrict__ offs, float* __restrict__ dinv) {
  __shared__ int sd[1024];
  int i = blockIdx.x * 1024 + threadIdx.x;
  int v = (i < NN) ? deg[i] : 0;
  sd[threadIdx.x] = v;
  __syncthreads();
  for (int s = 1; s < 1024; s <<= 1) {
    int t = (threadIdx.x >= s) ? sd[threadIdx.x - s] : 0;
    __syncthreads();
    sd[threadIdx.x] += t;
    __syncthreads();
  }
  if (i < NN) {
    offs[i] = cbase[blockIdx.x] + sd[threadIdx.x] - v;
    dinv[i] = (v > 0) ? rsqrtf((float)v) : 0.f;
  }
}

__global__ void k_fill(const int* __restrict__ ei, const int* __restrict__ flags,
                       const int* __restrict__ offs,
                       int* __restrict__ fill, const float* __restrict__ dinv,
                       int* __restrict__ colv, float* __restrict__ wgtv,
                       float* __restrict__ diag2) {
  int es = flags[1] + 1;
  int e = blockIdx.x * 256 + threadIdx.x;
  if (e >= EE) return;
  int r = ei[(size_t)e * es], c = ei[(size_t)(EE + e) * es];
  if (r == c) return;
  float w = dinv[r] * dinv[c];
  int p = offs[r] + atomicAdd(&fill[r], 1);
  colv[p] = c; wgtv[p] = w;
  int q = offs[c] + atomicAdd(&fill[c], 1);
  colv[q] = r; wgtv[q] = w;
  float w2 = w * w;
  atomicAdd(&diag2[r], w2);
  atomicAdd(&diag2[c], w2);
}

// ---------------- embed GEMM: h = relu(x @ W^T + b) + BN partial sums --------
__global__ __launch_bounds__(256) void k_embed(
    const void* __restrict__ xv, const void* __restrict__ Wv,
    const void* __restrict__ bEv, const int* __restrict__ flags,
    float* __restrict__ z, float* __restrict__ bnsum, float* __restrict__ bnsq) {
  __shared__ float s_sum[64], s_sq[64];
  const int fm = flags[0];
  const int wave = threadIdx.x >> 6, lane = threadIdx.x & 63;
  const int l15 = lane & 15, quad = lane >> 4;
  const int gid = blockIdx.x * 4 + wave;
  const bool valid = gid < NTILE;
  if (threadIdx.x < 64) { s_sum[threadIdx.x] = 0.f; s_sq[threadIdx.x] = 0.f; }
  __syncthreads();
  if (valid) {
    const int rb = gid * 16;
    f32x4 acc[4] = {};
    if (fm) {
      const float* xr = (const float*)xv + (size_t)(rb + l15) * IND + quad * 8;
      for (int ks = 0; ks < 16; ++ks) {
        bf16x8 ahi, alo;
        split8(xr + ks * 32, ahi, alo);
        #pragma unroll
        for (int nt = 0; nt < 4; ++nt) {
          bf16x8 bhi, blo;
          split8((const float*)Wv + (size_t)(nt * 16 + l15) * IND + ks * 32 + quad * 8, bhi, blo);
          acc[nt] = __builtin_amdgcn_mfma_f32_16x16x32_bf16(ahi, bhi, acc[nt], 0, 0, 0);
          acc[nt] = __builtin_amdgcn_mfma_f32_16x16x32_bf16(alo, bhi, acc[nt], 0, 0, 0);
          acc[nt] = __builtin_amdgcn_mfma_f32_16x16x32_bf16(ahi, blo, acc[nt], 0, 0, 0);
        }
      }
    } else {
      const unsigned short* xr = (const unsigned short*)xv + (size_t)(rb + l15) * IND + quad * 8;
      for (int ks = 0; ks < 16; ++ks) {
        bf16x8 a = *(const bf16x8*)(xr + ks * 32);
        #pragma unroll
        for (int nt = 0; nt < 4; ++nt) {
          bf16x8 b = *(const bf16x8*)((const unsigned short*)Wv +
                         (size_t)(nt * 16 + l15) * IND + ks * 32 + quad * 8);
          acc[nt] = __builtin_amdgcn_mfma_f32_16x16x32_bf16(a, b, acc[nt], 0, 0, 0);
        }
      }
    }
    #pragma unroll
    for (int nt = 0; nt < 4; ++nt) {
      int n = nt * 16 + l15;
      float bb = ldsc(bEv, n, fm);
      float ps = 0.f, pq = 0.f;
      #pragma unroll
      for (int r = 0; r < 4; ++r) {
        float v = fmaxf(acc[nt][r] + bb, 0.f);
        z[(size_t)(rb + quad * 4 + r) * ZD + n] = v;
        ps += v; pq += v * v;
      }
      ps += __shfl_xor(ps, 16); pq += __shfl_xor(pq, 16);
      ps += __shfl_xor(ps, 32); pq += __shfl_xor(pq, 32);
      if (quad == 0) { atomicAdd(&s_sum[n], ps); atomicAdd(&s_sq[n], pq); }
    }
  }
  __syncthreads();
  if (threadIdx.x < 64) {
    atomicAdd(&bnsum[threadIdx.x], s_sum[threadIdx.x]);
    atomicAdd(&bnsq[threadIdx.x], s_sq[threadIdx.x]);
  }
}

__global__ void k_bnfin(const float* __restrict__ bnsum, const float* __restrict__ bnsq,
                        const void* __restrict__ gv, const void* __restrict__ bv,
                        const int* __restrict__ flags, float* __restrict__ ab) {
  int c = threadIdx.x;
  int fm = flags[0];
  if (c < 64) {
    float mu = bnsum[c] * (1.0f / (float)NN);
    float var = bnsq[c] * (1.0f / (float)NN) - mu * mu;
    float a = ldsc(gv, c, fm) / sqrtf(var + 1e-5f);
    float b = ldsc(bv, c, fm) - mu * a;
    ab[c] = a; ab[64 + c] = b;
  }
}

__global__ void k_bnapply(float* __restrict__ z, const float* __restrict__ ab) {
  int i = blockIdx.x * 256 + threadIdx.x;   // NN*64 threads exactly
  int r = i >> 6, c = i & 63;
  float* p = &z[(size_t)r * ZD + c];
  *p = ab[c] * (*p) + ab[64 + c];
}

// ---------------- SPMM: y = A (xin [+ xin2]) - diag2 * (corr [+ corr2]) ------
__global__ __launch_bounds__(256) void k_spmm(
    const int* __restrict__ offs, const int* __restrict__ colv,
    const float* __restrict__ wgtv, const float* __restrict__ diag2,
    const float* __restrict__ xin, const float* __restrict__ xin2,
    const float* __restrict__ corr, const float* __restrict__ corr2,
    float* __restrict__ yout) {
  const int wave = threadIdx.x >> 6, lane = threadIdx.x & 63;
  const int r = blockIdx.x * 4 + wave;
  if (r >= NN) return;   // whole wave exits together; no barriers
  int s = offs[r], e = offs[r + 1];
  float acc = 0.f;
  if (xin2) {
    for (int j = s; j < e; ++j) {
      int c = colv[j]; float w = wgtv[j];
      size_t b = (size_t)c * ZD + lane;
      acc = fmaf(w, xin[b] + xin2[b], acc);
    }
  } else {
    for (int j = s; j < e; ++j) {
      int c = colv[j]; float w = wgtv[j];
      acc = fmaf(w, xin[(size_t)c * ZD + lane], acc);
    }
  }
  if (corr) {
    float cv = corr[(size_t)r * ZD + lane];
    if (corr2) cv += corr2[(size_t)r * ZD + lane];
    acc -= diag2[r] * cv;
  }
  yout[(size_t)r * ZD + lane] = acc;
}

// ---------------- final: out = relu(z @ W1^T + b1) @ W2^T + b2 ----------------
__global__ __launch_bounds__(256) void k_final(
    const float* __restrict__ z,
    const void* __restrict__ W1v, const void* __restrict__ b1v,
    const void* __restrict__ W2v, const void* __restrict__ b2v,
    const int* __restrict__ flags, void* __restrict__ outv) {
  __shared__ float tls[4][16][68];
  const int fm = flags[0];
  const int wave = threadIdx.x >> 6, lane = threadIdx.x & 63;
  const int l15 = lane & 15, quad = lane >> 4;
  const int gid = blockIdx.x * 4 + wave;
  const bool valid = gid < NTILE;
  if (valid) {
    const int rb = gid * 16;
    f32x4 acc[4] = {};
    const float* zr = z + (size_t)(rb + l15) * ZD + quad * 8;
    for (int ks = 0; ks < 10; ++ks) {
      bf16x8 ahi, alo;
      split8(zr + ks * 32, ahi, alo);
      #pragma unroll
      for (int nt = 0; nt < 4; ++nt) {
        bf16x8 bhi, blo;
        if (fm) {
          split8((const float*)W1v + (size_t)(nt * 16 + l15) * ZD + ks * 32 + quad * 8, bhi, blo);
        } else {
          bhi = *(const bf16x8*)((const unsigned short*)W1v +
                    (size_t)(nt * 16 + l15) * ZD + ks * 32 + quad * 8);
        }
        acc[nt] = __builtin_amdgcn_mfma_f32_16x16x32_bf16(ahi, bhi, acc[nt], 0, 0, 0);
        acc[nt] = __builtin_amdgcn_mfma_f32_16x16x32_bf16(alo, bhi, acc[nt], 0, 0, 0);
        if (fm)
          acc[nt] = __builtin_amdgcn_mfma_f32_16x16x32_bf16(ahi, blo, acc[nt], 0, 0, 0);
      }
    }
    #pragma unroll
    for (int nt = 0; nt < 4; ++nt) {
      int n = nt * 16 + l15;
      float bb = ldsc(b1v, n, fm);
      #pragma unroll
      for (int r = 0; r < 4; ++r)
        tls[wave][quad * 4 + r][n] = fmaxf(acc[nt][r] + bb, 0.f);
    }
  }
  __syncthreads();
  if (valid) {
    const int rb = gid * 16;
    f32x4 acc2[3] = {};
    #pragma unroll
    for (int ks = 0; ks < 2; ++ks) {
      bf16x8 ahi, alo;
      #pragma unroll
      for (int j = 0; j < 8; ++j) {
        float v = tls[wave][l15][ks * 32 + quad * 8 + j];
        __bf16 h = (__bf16)v;
        ahi[j] = h; alo[j] = (__bf16)(v - (float)h);
      }
      #pragma unroll
      for (int nt = 0; nt < 3; ++nt) {
        int n = nt * 16 + l15;
        bf16x8 bhi = {}, blo = {};
        if (n < CLS) {
          if (fm) split8((const float*)W2v + (size_t)n * HID + ks * 32 + quad * 8, bhi, blo);
          else    bhi = *(const bf16x8*)((const unsigned short*)W2v +
                          (size_t)n * HID + ks * 32 + quad * 8);
        }
        acc2[nt] = __builtin_amdgcn_mfma_f32_16x16x32_bf16(ahi, bhi, acc2[nt], 0, 0, 0);
        acc2[nt] = __builtin_amdgcn_mfma_f32_16x16x32_bf16(alo, bhi, acc2[nt], 0, 0, 0);
        if (fm)
          acc2[nt] = __builtin_amdgcn_mfma_f32_16x16x32_bf16(ahi, blo, acc2[nt], 0, 0, 0);
      }
    }
    #pragma unroll
    for (int nt = 0; nt < 3; ++nt) {
      int n = nt * 16 + l15;
      if (n < CLS) {
        float bb = ldsc(b2v, n, fm);
        #pragma unroll
        for (int r = 0; r < 4; ++r) {
          float v = acc2[nt][r] + bb;
          size_t oi = (size_t)(rb + quad * 4 + r) * CLS + n;
          if (fm) ((float*)outv)[oi] = v;
          else    ((unsigned short*)outv)[oi] = f2bf(v);
        }
      }
    }
  }
}

extern "C" void kernel_launch(void* const* d_in, const int* in_sizes, int n_in,
                              void* d_out, int out_size, void* d_ws, size_t ws_size,
                              hipStream_t stream) {
  (void)in_sizes; (void)n_in; (void)out_size; (void)ws_size;
  const void* x   = d_in[0];
  const int*  ei  = (const int*)d_in[1];
  const void* WE  = d_in[2];
  const void* bE  = d_in[3];
  const void* gam = d_in[4];
  const void* bet = d_in[5];
  const void* W1  = d_in[6];
  const void* b1  = d_in[7];
  const void* W2  = d_in[8];
  const void* b2  = d_in[9];

  float* wsf = (float*)d_ws;
  int*   wsi = (int*)d_ws;
  // word-offset layout; total ~142.8 MB
  int*   deg   = wsi + 0;          // NN     (zeroed)
  int*   fill  = wsi + 100000;     // NN     (zeroed)
  float* diag2 = wsf + 200000;     // NN     (zeroed)
  float* bnsum = wsf + 300000;     // 64     (zeroed)
  float* bnsq  = wsf + 300064;     // 64     (zeroed)
  int*   flags = wsi + 300128;     // 8
  float* bnab  = wsf + 300136;     // 128
  float* dinv  = wsf + 300264;     // NN
  int*   offs  = wsi + 400264;     // NN+1
  int*   cbase = wsi + 500272;     // NCH (+pad)
  int*   colv  = wsi + 500384;     // 2*EE
  float* wgtv  = wsf + 2100384;    // 2*EE
  float* z     = wsf + 3700384;    // NN*ZD (16B-aligned)

  hipMemsetAsync(d_ws, 0, (size_t)300128 * 4, stream);

  k_probe    <<<1, 256, 0, stream>>>((const unsigned short*)x, ei, flags);
  k_deg      <<<EE / 256, 256, 0, stream>>>(ei, flags, deg);
  k_chunksum <<<NCH, 1024, 0, stream>>>(deg, cbase);
  k_scanchunks<<<1, 64, 0, stream>>>(cbase, offs + NN);
  k_offs     <<<NCH, 1024, 0, stream>>>(deg, cbase, offs, dinv);
  k_fill     <<<EE / 256, 256, 0, stream>>>(ei, flags, offs, fill, dinv, colv, wgtv, diag2);

  k_embed    <<<(NTILE + 3) / 4, 256, 0, stream>>>(x, WE, bE, flags, z, bnsum, bnsq);
  k_bnfin    <<<1, 64, 0, stream>>>(bnsum, bnsq, gam, bet, flags, bnab);
  k_bnapply  <<<NN * 64 / 256, 256, 0, stream>>>(z, bnab);

  // hop 1: h1 = A h ; h2 = A h1 - diag2*h
  k_spmm<<<NN / 4, 256, 0, stream>>>(offs, colv, wgtv, diag2,
      z + 0, nullptr, nullptr, nullptr, z + 64);
  k_spmm<<<NN / 4, 256, 0, stream>>>(offs, colv, wgtv, diag2,
      z + 64, nullptr, z + 0, nullptr, z + 128);
  // hop 2: cur = h1+h2 (gathered on the fly); h3 = A cur ; h4 = A h3 - diag2*cur
  k_spmm<<<NN / 4, 256, 0, stream>>>(offs, colv, wgtv, diag2,
      z + 64, z + 128, nullptr, nullptr, z + 192);
  k_spmm<<<NN / 4, 256, 0, stream>>>(offs, colv, wgtv, diag2,
      z + 192, nullptr, z + 64, z + 128, z + 256);

  k_final<<<(NTILE + 3) / 4, 256, 0, stream>>>(z, W1, b1, W2, b2, flags, d_out);
}

// Round 3
// 900.587 us; speedup vs baseline: 1.4447x; 1.4447x over previous
//
#include <hip/hip_runtime.h>
#include <stdint.h>

// H2GCN forward on MI355X (gfx950). Round 2: SPMM MLP x4 unroll, packed edges,
// BN folded into SPMM1 epilogue, diag2 folded into SPMM1, cur materialized.
// Probe resolved inputs/outputs as f32 (kept dtype-robust branches).

typedef __bf16 bf16x8 __attribute__((ext_vector_type(8)));
typedef float  f32x4  __attribute__((ext_vector_type(4)));

#define NN   100000
#define EE   800000
#define IND  512
#define HID  64
#define ZD   320
#define CLS  40
#define NCH  98          // ceil(NN/1024)
#define NTILE (NN/16)    // 6250 row tiles of 16

static __device__ __forceinline__ float bf2f(unsigned short s) {
  unsigned int u = ((unsigned int)s) << 16;
  return __builtin_bit_cast(float, u);
}
static __device__ __forceinline__ unsigned short f2bf(float f) {
  unsigned int u = __builtin_bit_cast(unsigned int, f);
  u += 0x7FFFu + ((u >> 16) & 1u);   // RNE
  return (unsigned short)(u >> 16);
}
static __device__ __forceinline__ float ldsc(const void* p, int i, int fm) {
  return fm ? ((const float*)p)[i] : bf2f(((const unsigned short*)p)[i]);
}
static __device__ __forceinline__ float i2f(int v) { return __builtin_bit_cast(float, v); }
// split 8 consecutive f32 into hi/lo bf16 fragments
static __device__ __forceinline__ void split8(const float* p, bf16x8& hi, bf16x8& lo) {
  f32x4 u0 = *(const f32x4*)p;
  f32x4 u1 = *(const f32x4*)(p + 4);
  #pragma unroll
  for (int j = 0; j < 4; ++j) {
    float v0 = u0[j], v1 = u1[j];
    __bf16 h0 = (__bf16)v0, h1 = (__bf16)v1;
    hi[j] = h0;     lo[j] = (__bf16)(v0 - (float)h0);
    hi[4 + j] = h1; lo[4 + j] = (__bf16)(v1 - (float)h1);
  }
}

// ---------------- dtype probe ----------------
__global__ void k_probe(const unsigned short* __restrict__ xs,
                        const int* __restrict__ ei, int* __restrict__ flags) {
  __shared__ int cnt_big, cnt_nz;
  if (threadIdx.x == 0) { cnt_big = 0; cnt_nz = 0; }
  __syncthreads();
  unsigned short u = xs[threadIdx.x];
  int expf = (u >> 7) & 0xFF;
  if (expf >= 0x8D) atomicAdd(&cnt_big, 1);      // |bf16| >= 2^14 (or NaN/Inf)
  if (threadIdx.x < 128 && ei[2 * threadIdx.x + 1] != 0) atomicAdd(&cnt_nz, 1);
  __syncthreads();
  if (threadIdx.x == 0) {
    flags[0] = (cnt_big >= 2) ? 1 : 0;
    flags[1] = (cnt_nz < 64) ? 1 : 0;
  }
}

// ---------------- graph build ----------------
__global__ void k_deg(const int* __restrict__ ei, const int* __restrict__ flags,
                      int* __restrict__ deg) {
  int es = flags[1] + 1;
  int e = blockIdx.x * 256 + threadIdx.x;
  if (e >= EE) return;
  int r = ei[(size_t)e * es], c = ei[(size_t)(EE + e) * es];
  if (r != c) { atomicAdd(&deg[r], 1); atomicAdd(&deg[c], 1); }
}

__global__ void k_chunksum(const int* __restrict__ deg, int* __restrict__ csum) {
  __shared__ int sd[1024];
  int i = blockIdx.x * 1024 + threadIdx.x;
  sd[threadIdx.x] = (i < NN) ? deg[i] : 0;
  __syncthreads();
  for (int s = 512; s > 0; s >>= 1) {
    if (threadIdx.x < s) sd[threadIdx.x] += sd[threadIdx.x + s];
    __syncthreads();
  }
  if (threadIdx.x == 0) csum[blockIdx.x] = sd[0];
}

__global__ void k_scanchunks(int* __restrict__ csum, int* __restrict__ total) {
  if (threadIdx.x == 0) {
    int acc = 0;
    for (int i = 0; i < NCH; ++i) { int v = csum[i]; csum[i] = acc; acc += v; }
    total[0] = acc;
  }
}

__global__ void k_offs(const int* __restrict__ deg, const int* __restrict__ cbase,
                       int* __restrict__ offs, float* __restrict__ dinv) {
  __shared__ int sd[1024];
  int i = blockIdx.x * 1024 + threadIdx.x;
  int v = (i < NN) ? deg[i] : 0;
  sd[threadIdx.x] = v;
  __syncthreads();
  for (int s = 1; s < 1024; s <<= 1) {
    int t = (threadIdx.x >= s) ? sd[threadIdx.x - s] : 0;
    __syncthreads();
    sd[threadIdx.x] += t;
    __syncthreads();
  }
  if (i < NN) {
    offs[i] = cbase[blockIdx.x] + sd[threadIdx.x] - v;
    dinv[i] = (v > 0) ? rsqrtf((float)v) : 0.f;
  }
}

__global__ void k_fill(const int* __restrict__ ei, const int* __restrict__ flags,
                       const int* __restrict__ offs,
                       int* __restrict__ fill, const float* __restrict__ dinv,
                       int2* __restrict__ ep) {
  int es = flags[1] + 1;
  int e = blockIdx.x * 256 + threadIdx.x;
  if (e >= EE) return;
  int r = ei[(size_t)e * es], c = ei[(size_t)(EE + e) * es];
  if (r == c) return;
  float w = dinv[r] * dinv[c];
  int wb = __builtin_bit_cast(int, w);
  int p = offs[r] + atomicAdd(&fill[r], 1);
  ep[p] = make_int2(c, wb);
  int q = offs[c] + atomicAdd(&fill[c], 1);
  ep[q] = make_int2(r, wb);
}

// ---------------- embed GEMM: hraw = relu(x @ W^T + b) + BN partial sums -----
__global__ __launch_bounds__(256) void k_embed(
    const void* __restrict__ xv, const void* __restrict__ Wv,
    const void* __restrict__ bEv, const int* __restrict__ flags,
    float* __restrict__ hraw, float* __restrict__ bnsum, float* __restrict__ bnsq) {
  __shared__ float s_sum[64], s_sq[64];
  const int fm = flags[0];
  const int wave = threadIdx.x >> 6, lane = threadIdx.x & 63;
  const int l15 = lane & 15, quad = lane >> 4;
  const int gid = blockIdx.x * 4 + wave;
  const bool valid = gid < NTILE;
  if (threadIdx.x < 64) { s_sum[threadIdx.x] = 0.f; s_sq[threadIdx.x] = 0.f; }
  __syncthreads();
  if (valid) {
    const int rb = gid * 16;
    f32x4 acc[4] = {};
    if (fm) {
      const float* xr = (const float*)xv + (size_t)(rb + l15) * IND + quad * 8;
      for (int ks = 0; ks < 16; ++ks) {
        bf16x8 ahi, alo;
        split8(xr + ks * 32, ahi, alo);
        #pragma unroll
        for (int nt = 0; nt < 4; ++nt) {
          bf16x8 bhi, blo;
          split8((const float*)Wv + (size_t)(nt * 16 + l15) * IND + ks * 32 + quad * 8, bhi, blo);
          acc[nt] = __builtin_amdgcn_mfma_f32_16x16x32_bf16(ahi, bhi, acc[nt], 0, 0, 0);
          acc[nt] = __builtin_amdgcn_mfma_f32_16x16x32_bf16(alo, bhi, acc[nt], 0, 0, 0);
          acc[nt] = __builtin_amdgcn_mfma_f32_16x16x32_bf16(ahi, blo, acc[nt], 0, 0, 0);
        }
      }
    } else {
      const unsigned short* xr = (const unsigned short*)xv + (size_t)(rb + l15) * IND + quad * 8;
      for (int ks = 0; ks < 16; ++ks) {
        bf16x8 a = *(const bf16x8*)(xr + ks * 32);
        #pragma unroll
        for (int nt = 0; nt < 4; ++nt) {
          bf16x8 b = *(const bf16x8*)((const unsigned short*)Wv +
                         (size_t)(nt * 16 + l15) * IND + ks * 32 + quad * 8);
          acc[nt] = __builtin_amdgcn_mfma_f32_16x16x32_bf16(a, b, acc[nt], 0, 0, 0);
        }
      }
    }
    #pragma unroll
    for (int nt = 0; nt < 4; ++nt) {
      int n = nt * 16 + l15;
      float bb = ldsc(bEv, n, fm);
      float ps = 0.f, pq = 0.f;
      #pragma unroll
      for (int r = 0; r < 4; ++r) {
        float v = fmaxf(acc[nt][r] + bb, 0.f);
        hraw[(size_t)(rb + quad * 4 + r) * 64 + n] = v;
        ps += v; pq += v * v;
      }
      ps += __shfl_xor(ps, 16); pq += __shfl_xor(pq, 16);
      ps += __shfl_xor(ps, 32); pq += __shfl_xor(pq, 32);
      if (quad == 0) { atomicAdd(&s_sum[n], ps); atomicAdd(&s_sq[n], pq); }
    }
  }
  __syncthreads();
  if (threadIdx.x < 64) {
    atomicAdd(&bnsum[threadIdx.x], s_sum[threadIdx.x]);
    atomicAdd(&bnsq[threadIdx.x], s_sq[threadIdx.x]);
  }
}

__global__ void k_bnfin(const float* __restrict__ bnsum, const float* __restrict__ bnsq,
                        const void* __restrict__ gv, const void* __restrict__ bv,
                        const int* __restrict__ flags, float* __restrict__ ab) {
  int c = threadIdx.x;
  int fm = flags[0];
  if (c < 64) {
    float mu = bnsum[c] * (1.0f / (float)NN);
    float var = bnsq[c] * (1.0f / (float)NN) - mu * mu;
    float a = ldsc(gv, c, fm) / sqrtf(var + 1e-5f);
    float b = ldsc(bv, c, fm) - mu * a;
    ab[c] = a; ab[64 + c] = b;
  }
}

// ---------------- SPMM kernels (x4-unrolled gather, 4 accumulators) ----------
// SPMM1: gather raw h; z0 = BN(hraw[r]); z1 = a*Sum(w*hraw) + b*Sum(w); diag2 = Sum(w^2)
__global__ __launch_bounds__(256) void k_sp1(
    const int* __restrict__ offs, const int2* __restrict__ ep,
    const float* __restrict__ hraw, const float* __restrict__ bnab,
    float* __restrict__ diag2, float* __restrict__ z) {
  const int r = blockIdx.x * 4 + (threadIdx.x >> 6);
  const int lane = threadIdx.x & 63;
  if (r >= NN) return;
  int s = offs[r], e = offs[r + 1];
  float a0 = 0, a1 = 0, a2 = 0, a3 = 0, sw = 0, sq = 0;
  int j = s;
  for (; j + 4 <= e; j += 4) {
    int2 p0 = ep[j], p1 = ep[j + 1], p2 = ep[j + 2], p3 = ep[j + 3];
    float x0 = hraw[(size_t)p0.x * 64 + lane];
    float x1 = hraw[(size_t)p1.x * 64 + lane];
    float x2 = hraw[(size_t)p2.x * 64 + lane];
    float x3 = hraw[(size_t)p3.x * 64 + lane];
    float w0 = i2f(p0.y), w1 = i2f(p1.y), w2 = i2f(p2.y), w3 = i2f(p3.y);
    a0 = fmaf(w0, x0, a0); a1 = fmaf(w1, x1, a1);
    a2 = fmaf(w2, x2, a2); a3 = fmaf(w3, x3, a3);
    sw += (w0 + w1) + (w2 + w3);
    sq = fmaf(w3, w3, fmaf(w2, w2, fmaf(w1, w1, fmaf(w0, w0, sq))));
  }
  for (; j < e; ++j) {
    int2 p = ep[j];
    float w = i2f(p.y);
    a0 = fmaf(w, hraw[(size_t)p.x * 64 + lane], a0);
    sw += w; sq = fmaf(w, w, sq);
  }
  float acc = (a0 + a1) + (a2 + a3);
  float ga = bnab[lane], gb = bnab[64 + lane];
  size_t zr = (size_t)r * ZD;
  z[zr + lane] = fmaf(ga, hraw[(size_t)r * 64 + lane], gb);
  z[zr + 64 + lane] = ga * acc + gb * sw;
  if (lane == 0) diag2[r] = sq;
}

// SPMM2: gather h1 (z+64); h2 = acc - diag2*z0; write z2 and cur = h1[r] + h2
__global__ __launch_bounds__(256) void k_sp2(
    const int* __restrict__ offs, const int2* __restrict__ ep,
    const float* __restrict__ diag2, float* __restrict__ z,
    float* __restrict__ cur) {
  const int r = blockIdx.x * 4 + (threadIdx.x >> 6);
  const int lane = threadIdx.x & 63;
  if (r >= NN) return;
  int s = offs[r], e = offs[r + 1];
  const float* xin = z + 64;
  float a0 = 0, a1 = 0, a2 = 0, a3 = 0;
  int j = s;
  for (; j + 4 <= e; j += 4) {
    int2 p0 = ep[j], p1 = ep[j + 1], p2 = ep[j + 2], p3 = ep[j + 3];
    float x0 = xin[(size_t)p0.x * ZD + lane];
    float x1 = xin[(size_t)p1.x * ZD + lane];
    float x2 = xin[(size_t)p2.x * ZD + lane];
    float x3 = xin[(size_t)p3.x * ZD + lane];
    a0 = fmaf(i2f(p0.y), x0, a0); a1 = fmaf(i2f(p1.y), x1, a1);
    a2 = fmaf(i2f(p2.y), x2, a2); a3 = fmaf(i2f(p3.y), x3, a3);
  }
  for (; j < e; ++j) {
    int2 p = ep[j];
    a0 = fmaf(i2f(p.y), xin[(size_t)p.x * ZD + lane], a0);
  }
  float acc = (a0 + a1) + (a2 + a3);
  size_t zr = (size_t)r * ZD;
  float h2 = acc - diag2[r] * z[zr + lane];
  z[zr + 128 + lane] = h2;
  cur[(size_t)r * 64 + lane] = z[zr + 64 + lane] + h2;
}

// SPMM3/4 generic: gather xin (stride xs); y = acc [- diag2*corr64]; write z+zoff
__global__ __launch_bounds__(256) void k_spg(
    const int* __restrict__ offs, const int2* __restrict__ ep,
    const float* __restrict__ xin, long xs,
    const float* __restrict__ diag2, const float* __restrict__ corr64,
    float* __restrict__ yout) {
  const int r = blockIdx.x * 4 + (threadIdx.x >> 6);
  const int lane = threadIdx.x & 63;
  if (r >= NN) return;
  int s = offs[r], e = offs[r + 1];
  float a0 = 0, a1 = 0, a2 = 0, a3 = 0;
  int j = s;
  for (; j + 4 <= e; j += 4) {
    int2 p0 = ep[j], p1 = ep[j + 1], p2 = ep[j + 2], p3 = ep[j + 3];
    float x0 = xin[(size_t)p0.x * xs + lane];
    float x1 = xin[(size_t)p1.x * xs + lane];
    float x2 = xin[(size_t)p2.x * xs + lane];
    float x3 = xin[(size_t)p3.x * xs + lane];
    a0 = fmaf(i2f(p0.y), x0, a0); a1 = fmaf(i2f(p1.y), x1, a1);
    a2 = fmaf(i2f(p2.y), x2, a2); a3 = fmaf(i2f(p3.y), x3, a3);
  }
  for (; j < e; ++j) {
    int2 p = ep[j];
    a0 = fmaf(i2f(p.y), xin[(size_t)p.x * xs + lane], a0);
  }
  float acc = (a0 + a1) + (a2 + a3);
  if (corr64) acc -= diag2[r] * corr64[(size_t)r * 64 + lane];
  yout[(size_t)r * ZD + lane] = acc;
}

// ---------------- final: out = relu(z @ W1^T + b1) @ W2^T + b2 ----------------
__global__ __launch_bounds__(256) void k_final(
    const float* __restrict__ z,
    const void* __restrict__ W1v, const void* __restrict__ b1v,
    const void* __restrict__ W2v, const void* __restrict__ b2v,
    const int* __restrict__ flags, void* __restrict__ outv) {
  __shared__ float tls[4][16][68];
  const int fm = flags[0];
  const int wave = threadIdx.x >> 6, lane = threadIdx.x & 63;
  const int l15 = lane & 15, quad = lane >> 4;
  const int gid = blockIdx.x * 4 + wave;
  const bool valid = gid < NTILE;
  if (valid) {
    const int rb = gid * 16;
    f32x4 acc[4] = {};
    const float* zr = z + (size_t)(rb + l15) * ZD + quad * 8;
    for (int ks = 0; ks < 10; ++ks) {
      bf16x8 ahi, alo;
      split8(zr + ks * 32, ahi, alo);
      #pragma unroll
      for (int nt = 0; nt < 4; ++nt) {
        bf16x8 bhi, blo;
        if (fm) {
          split8((const float*)W1v + (size_t)(nt * 16 + l15) * ZD + ks * 32 + quad * 8, bhi, blo);
        } else {
          bhi = *(const bf16x8*)((const unsigned short*)W1v +
                    (size_t)(nt * 16 + l15) * ZD + ks * 32 + quad * 8);
        }
        acc[nt] = __builtin_amdgcn_mfma_f32_16x16x32_bf16(ahi, bhi, acc[nt], 0, 0, 0);
        acc[nt] = __builtin_amdgcn_mfma_f32_16x16x32_bf16(alo, bhi, acc[nt], 0, 0, 0);
        if (fm)
          acc[nt] = __builtin_amdgcn_mfma_f32_16x16x32_bf16(ahi, blo, acc[nt], 0, 0, 0);
      }
    }
    #pragma unroll
    for (int nt = 0; nt < 4; ++nt) {
      int n = nt * 16 + l15;
      float bb = ldsc(b1v, n, fm);
      #pragma unroll
      for (int r = 0; r < 4; ++r)
        tls[wave][quad * 4 + r][n] = fmaxf(acc[nt][r] + bb, 0.f);
    }
  }
  __syncthreads();
  if (valid) {
    const int rb = gid * 16;
    f32x4 acc2[3] = {};
    #pragma unroll
    for (int ks = 0; ks < 2; ++ks) {
      bf16x8 ahi, alo;
      #pragma unroll
      for (int j = 0; j < 8; ++j) {
        float v = tls[wave][l15][ks * 32 + quad * 8 + j];
        __bf16 h = (__bf16)v;
        ahi[j] = h; alo[j] = (__bf16)(v - (float)h);
      }
      #pragma unroll
      for (int nt = 0; nt < 3; ++nt) {
        int n = nt * 16 + l15;
        bf16x8 bhi = {}, blo = {};
        if (n < CLS) {
          if (fm) split8((const float*)W2v + (size_t)n * HID + ks * 32 + quad * 8, bhi, blo);
          else    bhi = *(const bf16x8*)((const unsigned short*)W2v +
                          (size_t)n * HID + ks * 32 + quad * 8);
        }
        acc2[nt] = __builtin_amdgcn_mfma_f32_16x16x32_bf16(ahi, bhi, acc2[nt], 0, 0, 0);
        acc2[nt] = __builtin_amdgcn_mfma_f32_16x16x32_bf16(alo, bhi, acc2[nt], 0, 0, 0);
        if (fm)
          acc2[nt] = __builtin_amdgcn_mfma_f32_16x16x32_bf16(ahi, blo, acc2[nt], 0, 0, 0);
      }
    }
    #pragma unroll
    for (int nt = 0; nt < 3; ++nt) {
      int n = nt * 16 + l15;
      if (n < CLS) {
        float bb = ldsc(b2v, n, fm);
        #pragma unroll
        for (int r = 0; r < 4; ++r) {
          float v = acc2[nt][r] + bb;
          size_t oi = (size_t)(rb + quad * 4 + r) * CLS + n;
          if (fm) ((float*)outv)[oi] = v;
          else    ((unsigned short*)outv)[oi] = f2bf(v);
        }
      }
    }
  }
}

extern "C" void kernel_launch(void* const* d_in, const int* in_sizes, int n_in,
                              void* d_out, int out_size, void* d_ws, size_t ws_size,
                              hipStream_t stream) {
  (void)in_sizes; (void)n_in; (void)out_size; (void)ws_size;
  const void* x   = d_in[0];
  const int*  ei  = (const int*)d_in[1];
  const void* WE  = d_in[2];
  const void* bE  = d_in[3];
  const void* gam = d_in[4];
  const void* bet = d_in[5];
  const void* W1  = d_in[6];
  const void* b1  = d_in[7];
  const void* W2  = d_in[8];
  const void* b2  = d_in[9];

  float* wsf = (float*)d_ws;
  int*   wsi = (int*)d_ws;
  // word-offset layout; total ~168.4 MB (same footprint as round-0, known OK)
  int*   deg   = wsi + 0;          // NN     (zeroed)
  int*   fill  = wsi + 100000;     // NN     (zeroed)
  float* bnsum = wsf + 200000;     // 64     (zeroed)
  float* bnsq  = wsf + 200064;     // 64     (zeroed)
  int*   flags = wsi + 200128;     // 8
  float* bnab  = wsf + 200136;     // 128
  float* dinv  = wsf + 200264;     // NN
  int*   offs  = wsi + 300264;     // NN+1
  int*   cbase = wsi + 400272;     // NCH (+pad to 400384)
  int2*  ep    = (int2*)(wsi + 400384);   // 1.6M edges (3.2M words)
  float* diag2 = wsf + 3600384;    // NN
  float* hraw  = wsf + 3700384;    // NN*64  (aliased as `cur` after SPMM1)
  float* z     = wsf + 10100384;   // NN*ZD
  float* cur   = hraw;             // alias: hraw dead after SPMM1

  hipMemsetAsync(d_ws, 0, (size_t)200128 * 4, stream);

  k_probe     <<<1, 256, 0, stream>>>((const unsigned short*)x, ei, flags);
  k_deg       <<<EE / 256, 256, 0, stream>>>(ei, flags, deg);
  k_chunksum  <<<NCH, 1024, 0, stream>>>(deg, cbase);
  k_scanchunks<<<1, 64, 0, stream>>>(cbase, offs + NN);
  k_offs      <<<NCH, 1024, 0, stream>>>(deg, cbase, offs, dinv);
  k_fill      <<<EE / 256, 256, 0, stream>>>(ei, flags, offs, fill, dinv, ep);

  k_embed     <<<(NTILE + 3) / 4, 256, 0, stream>>>(x, WE, bE, flags, hraw, bnsum, bnsq);
  k_bnfin     <<<1, 64, 0, stream>>>(bnsum, bnsq, gam, bet, flags, bnab);

  k_sp1<<<NN / 4, 256, 0, stream>>>(offs, ep, hraw, bnab, diag2, z);
  k_sp2<<<NN / 4, 256, 0, stream>>>(offs, ep, diag2, z, cur);
  k_spg<<<NN / 4, 256, 0, stream>>>(offs, ep, cur, 64, diag2, nullptr, z + 192);
  k_spg<<<NN / 4, 256, 0, stream>>>(offs, ep, z + 192, ZD, diag2, cur, z + 256);

  k_final<<<(NTILE + 3) / 4, 256, 0, stream>>>(z, W1, b1, W2, b2, flags, d_out);
}